// Round 8
// baseline (229.717 us; speedup 1.0000x reference)
//
#include <hip/hip_runtime.h>
#include <math.h>

#define N_NODES 10000
#define N_EDGES 160000
#define CAP 64
#define GRID 512

typedef short bf16x8 __attribute__((ext_vector_type(8)));
typedef float f32x4 __attribute__((ext_vector_type(4)));

// ---------- helpers ----------
__device__ __forceinline__ float bf2f(unsigned short u) {
    return __uint_as_float(((unsigned int)u) << 16);
}
__device__ __forceinline__ unsigned short f2bf(float f) {
    unsigned int x = __float_as_uint(f);
    unsigned int r = (x + 0x7fffu + ((x >> 16) & 1u)) >> 16;   // RNE
    return (unsigned short)r;
}
__device__ __forceinline__ float softplus_f(float x) {
    return fmaxf(x, 0.f) + log1pf(__expf(-fabsf(x)));
}

// ---------- sense-reversing grid barrier (R5-validated: relaxed polls) ----------
__device__ unsigned int g_cnt = 0;
__device__ unsigned int g_sense = 0;

__device__ __forceinline__ void gbar() {
    __syncthreads();
    if (threadIdx.x == 0) {
        unsigned int e = __hip_atomic_load(&g_sense, __ATOMIC_RELAXED, __HIP_MEMORY_SCOPE_AGENT);
        unsigned int old = __hip_atomic_fetch_add(&g_cnt, 1, __ATOMIC_RELEASE, __HIP_MEMORY_SCOPE_AGENT);
        if (old == GRID - 1) {
            __hip_atomic_store(&g_cnt, 0, __ATOMIC_RELAXED, __HIP_MEMORY_SCOPE_AGENT);
            __hip_atomic_fetch_add(&g_sense, 1, __ATOMIC_RELEASE, __HIP_MEMORY_SCOPE_AGENT);
        } else {
            while (__hip_atomic_load(&g_sense, __ATOMIC_RELAXED, __HIP_MEMORY_SCOPE_AGENT) == e)
                __builtin_amdgcn_s_sleep(2);
        }
        __builtin_amdgcn_fence(__ATOMIC_ACQUIRE, "agent");
    }
    __syncthreads();
}

// ---------- the whole layer, one launch ----------
// LDS union: phase1 uses first 32KB as float[8192]; phase2 layout:
//   [0      .. 32767]  aldsb: 16 waves x 512 f32 (alpha per edge)
//   [32768  .. 51455]  accL : 16 rows x 584 ushort (V rows, bf16)
//   [51456  .. 55551]  sldsb: 16 waves x 64 int (sender ids)
__global__ void __launch_bounds__(1024, 8) k_fused(const float* __restrict__ x,
                                                   const int* __restrict__ ei,
                                                   const float* __restrict__ el,
                                                   const float* __restrict__ wproj,
                                                   const float* __restrict__ wrad,
                                                   const float* __restrict__ wtan,
                                                   const float* __restrict__ rsc,
                                                   const float* __restrict__ tsc,
                                                   const float* __restrict__ rdls,
                                                   const float* __restrict__ tb,
                                                   const float* __restrict__ tw,
                                                   const float* __restrict__ wout,
                                                   float* __restrict__ rts,
                                                   int* __restrict__ cur,
                                                   int2* __restrict__ sbuf,
                                                   unsigned short* __restrict__ wppT,
                                                   float* __restrict__ out) {
    __shared__ __align__(16) char smem[55552];
    int b = blockIdx.x;
    int t = threadIdx.x;
    int wid = t >> 6, lane = t & 63;

    // ---- phase 0: zero bucket counters ----
    {
        int idx = b * 1024 + t;
        if (idx < N_NODES) cur[idx] = 0;
    }
    gbar();

    // ---- phase 1: one task per block, mapped to high block ids (336..511) ----
    if (b >= 336) {
        int task = 511 - b;                    // 0..175
        if (task < 10) {
            // scores -> rts[n][0..3]=r, [4..7]=t  (f32 exact path)
            float* vrl = (float*)smem;         // 256 floats
            float* vtl = vrl + 256;
            if (t < 256) {
                int h = t >> 6, f = t & 63;
                const float* wrow = wproj + h * 4096 + f * 64;
                const float* rsp = rsc + h * 64;
                const float* tsp = tsc + h * 64;
                float ar = 0.f, at = 0.f;
                for (int g = 0; g < 64; ++g) {
                    float w = wrow[g];
                    ar += w * rsp[g];
                    at += w * tsp[g];
                }
                vrl[t] = ar;
                vtl[t] = at;
            }
            __syncthreads();
            int n = task * 1024 + t;
            if (n < N_NODES) {
                const float4* xr = (const float4*)(x + n * 64);
                float accr[4] = {0.f, 0.f, 0.f, 0.f};
                float acct[4] = {0.f, 0.f, 0.f, 0.f};
                for (int i = 0; i < 16; ++i) {
                    float4 xv = xr[i];
#pragma unroll
                    for (int h = 0; h < 4; ++h) {
                        float4 a = ((const float4*)vrl)[h * 16 + i];
                        accr[h] += xv.x * a.x + xv.y * a.y + xv.z * a.z + xv.w * a.w;
                        float4 bb = ((const float4*)vtl)[h * 16 + i];
                        acct[h] += xv.x * bb.x + xv.y * bb.y + xv.z * bb.z + xv.w * bb.w;
                    }
                }
                ((float4*)rts)[n * 2]     = make_float4(accr[0], accr[1], accr[2], accr[3]);
                ((float4*)rts)[n * 2 + 1] = make_float4(acct[0], acct[1], acct[2], acct[3]);
            }
        } else if (task < 167) {
            // bucket edges by receiver
            int e = (task - 10) * 1024 + t;
            if (e < N_EDGES) {
                int s = ei[e];
                int r = ei[N_EDGES + e];
                float len = el[e];
                int pos = atomicAdd(&cur[r], 1);
                if (pos < CAP) sbuf[r * CAP + pos] = make_int2(s, __float_as_int(len));
            }
        } else {
            // W'' precompute: W''_k = Wk @ Wout * 0.25 (k=8: -sum), transposed bf16
            int k = task - 167;                // 0..8
            float* wo = (float*)smem;          // wout [g][c], 16 KB
            float* am = wo + 4096;             // A    [f][g], 16 KB
            for (int i = 0; i < 4; ++i) wo[t + 1024 * i] = wout[t + 1024 * i];
            if (k < 8) {
                const float* M = (k < 4) ? (wrad + k * 4096) : (wtan + (k - 4) * 4096);
                for (int i = 0; i < 4; ++i) am[t + 1024 * i] = M[t + 1024 * i];
            } else {
                for (int i = 0; i < 4; ++i) {
                    int e = t + 1024 * i;
                    float s = 0.f;
#pragma unroll
                    for (int h = 0; h < 4; ++h) s += wrad[h * 4096 + e] + wtan[h * 4096 + e];
                    am[e] = -s;
                }
            }
            __syncthreads();
            int c = t & 63;
            int fg = t >> 6;                   // 0..15
#pragma unroll
            for (int j = 0; j < 4; ++j) {
                int f = fg * 4 + j;
                float acc = 0.f;
                for (int g = 0; g < 64; ++g) acc += am[f * 64 + g] * wo[g * 64 + c];
                wppT[c * 576 + k * 64 + f] = f2bf(acc * 0.25f);
            }
        }
    }
    gbar();

    // ---- phase 2: 625 16-node tiles over 512 blocks (blocks 0..112 run 2 rounds) ----
    float* aldsb = (float*)smem;
    unsigned short* accL = (unsigned short*)(smem + 32768);
    int* sldsb = (int*)(smem + 51456);
    float* alds = aldsb + wid * 512;
    int*   slds = sldsb + wid * 64;

    float scale = softplus_f(rdls[0]);
    float tb0 = tb[0], tb1 = tb[1], tb2 = tb[2], tb3 = tb[3];
    float tw0 = tw[0], tw1 = tw[1], tw2 = tw[2], tw3 = tw[3];

    for (int r = 0; r < 2; ++r) {
        int bb = b + r * GRID;
        if (bb >= 625) break;                  // uniform per block
        if (r == 1) __syncthreads();           // accL reads of round 0 done
        int n = bb * 16 + wid;
        int deg = min(cur[n], CAP);

        float4 rsr = ((const float4*)rts)[n * 2];
        float4 tsr = ((const float4*)rts)[n * 2 + 1];

        const float NEG = -3.402823466e38f;
        float rl0 = NEG, rl1 = NEG, rl2 = NEG, rl3 = NEG;
        float tl0 = NEG, tl1 = NEG, tl2 = NEG, tl3 = NEG;
        int s_e = 0;
        if (lane < deg) {
            int2 sl = sbuf[n * CAP + lane];
            s_e = sl.x;
            float len = __int_as_float(sl.y);
            float4 rss = ((const float4*)rts)[s_e * 2];
            float4 tss = ((const float4*)rts)[s_e * 2 + 1];
            float sl0 = scale * len;
            float i0 = 1.f / (softplus_f(tb0 + tw0 * len) + 1e-4f);
            float i1 = 1.f / (softplus_f(tb1 + tw1 * len) + 1e-4f);
            float i2 = 1.f / (softplus_f(tb2 + tw2 * len) + 1e-4f);
            float i3 = 1.f / (softplus_f(tb3 + tw3 * len) + 1e-4f);
            rl0 = ((rss.x - rsr.x) - sl0) * i0;
            rl1 = ((rss.y - rsr.y) - sl0) * i1;
            rl2 = ((rss.z - rsr.z) - sl0) * i2;
            rl3 = ((rss.w - rsr.w) - sl0) * i3;
            tl0 = tss.x - tsr.x;
            tl1 = tss.y - tsr.y;
            tl2 = tss.z - tsr.z;
            tl3 = tss.w - tsr.w;
        }
        float mr0 = rl0, mr1 = rl1, mr2 = rl2, mr3 = rl3;
        float mt0 = tl0, mt1 = tl1, mt2 = tl2, mt3 = tl3;
#pragma unroll
        for (int d = 32; d >= 1; d >>= 1) {
            mr0 = fmaxf(mr0, __shfl_xor(mr0, d)); mr1 = fmaxf(mr1, __shfl_xor(mr1, d));
            mr2 = fmaxf(mr2, __shfl_xor(mr2, d)); mr3 = fmaxf(mr3, __shfl_xor(mr3, d));
            mt0 = fmaxf(mt0, __shfl_xor(mt0, d)); mt1 = fmaxf(mt1, __shfl_xor(mt1, d));
            mt2 = fmaxf(mt2, __shfl_xor(mt2, d)); mt3 = fmaxf(mt3, __shfl_xor(mt3, d));
        }
        float er0 = 0.f, er1 = 0.f, er2 = 0.f, er3 = 0.f;
        float et0 = 0.f, et1 = 0.f, et2 = 0.f, et3 = 0.f;
        if (lane < deg) {
            er0 = __expf(rl0 - mr0); er1 = __expf(rl1 - mr1);
            er2 = __expf(rl2 - mr2); er3 = __expf(rl3 - mr3);
            et0 = __expf(tl0 - mt0); et1 = __expf(tl1 - mt1);
            et2 = __expf(tl2 - mt2); et3 = __expf(tl3 - mt3);
        }
        float sr0 = er0, sr1 = er1, sr2 = er2, sr3 = er3;
        float st0 = et0, st1 = et1, st2 = et2, st3 = et3;
#pragma unroll
        for (int d = 32; d >= 1; d >>= 1) {
            sr0 += __shfl_xor(sr0, d); sr1 += __shfl_xor(sr1, d);
            sr2 += __shfl_xor(sr2, d); sr3 += __shfl_xor(sr3, d);
            st0 += __shfl_xor(st0, d); st1 += __shfl_xor(st1, d);
            st2 += __shfl_xor(st2, d); st3 += __shfl_xor(st3, d);
        }
        if (lane < deg) {
            float* ap = alds + lane * 8;
            ((float4*)ap)[0] = make_float4(er0 / sr0, er1 / sr1, er2 / sr2, er3 / sr3);
            ((float4*)ap)[1] = make_float4(et0 / st0, et1 / st1, et2 / st2, et3 / st3);
            slds[lane] = s_e;
        }

        // accumulate V row: lane = feature f; 9 accumulators; 4-way unrolled
        float a0 = 0.f, a1 = 0.f, a2 = 0.f, a3 = 0.f;
        float b0 = 0.f, b1 = 0.f, b2 = 0.f, b3 = 0.f;
        int i = 0;
        for (; i + 4 <= deg; i += 4) {
            int s0 = slds[i], s1 = slds[i + 1], s2 = slds[i + 2], s3 = slds[i + 3];
            float xv0 = x[s0 * 64 + lane];
            float xv1 = x[s1 * 64 + lane];
            float xv2 = x[s2 * 64 + lane];
            float xv3 = x[s3 * 64 + lane];
            float4 ar0 = ((const float4*)(alds + i * 8))[0];
            float4 at0 = ((const float4*)(alds + i * 8))[1];
            float4 ar1 = ((const float4*)(alds + (i + 1) * 8))[0];
            float4 at1 = ((const float4*)(alds + (i + 1) * 8))[1];
            float4 ar2 = ((const float4*)(alds + (i + 2) * 8))[0];
            float4 at2 = ((const float4*)(alds + (i + 2) * 8))[1];
            float4 ar3 = ((const float4*)(alds + (i + 3) * 8))[0];
            float4 at3 = ((const float4*)(alds + (i + 3) * 8))[1];
            a0 += ar0.x * xv0 + ar1.x * xv1 + ar2.x * xv2 + ar3.x * xv3;
            a1 += ar0.y * xv0 + ar1.y * xv1 + ar2.y * xv2 + ar3.y * xv3;
            a2 += ar0.z * xv0 + ar1.z * xv1 + ar2.z * xv2 + ar3.z * xv3;
            a3 += ar0.w * xv0 + ar1.w * xv1 + ar2.w * xv2 + ar3.w * xv3;
            b0 += at0.x * xv0 + at1.x * xv1 + at2.x * xv2 + at3.x * xv3;
            b1 += at0.y * xv0 + at1.y * xv1 + at2.y * xv2 + at3.y * xv3;
            b2 += at0.z * xv0 + at1.z * xv1 + at2.z * xv2 + at3.z * xv3;
            b3 += at0.w * xv0 + at1.w * xv1 + at2.w * xv2 + at3.w * xv3;
        }
        for (; i < deg; ++i) {
            int s0 = slds[i];
            float xv0 = x[s0 * 64 + lane];
            float4 ar0 = ((const float4*)(alds + i * 8))[0];
            float4 at0 = ((const float4*)(alds + i * 8))[1];
            a0 += ar0.x * xv0; a1 += ar0.y * xv0; a2 += ar0.z * xv0; a3 += ar0.w * xv0;
            b0 += at0.x * xv0; b1 += at0.y * xv0; b2 += at0.z * xv0; b3 += at0.w * xv0;
        }
        float c8 = (deg > 0) ? x[n * 64 + lane] : 0.f;   // receiver slot (sign in W''_8)

        unsigned short* arow = accL + wid * 584;
        arow[0 * 64 + lane] = f2bf(a0);
        arow[1 * 64 + lane] = f2bf(a1);
        arow[2 * 64 + lane] = f2bf(a2);
        arow[3 * 64 + lane] = f2bf(a3);
        arow[4 * 64 + lane] = f2bf(b0);
        arow[5 * 64 + lane] = f2bf(b1);
        arow[6 * 64 + lane] = f2bf(b2);
        arow[7 * 64 + lane] = f2bf(b3);
        arow[8 * 64 + lane] = f2bf(c8);
        __syncthreads();

        // stage B: [16 x 576] @ W''T -> out[16 x 64]; waves 0..3
        if (wid < 4) {
            int c = lane & 15, q = lane >> 4;
            f32x4 dacc = {0.f, 0.f, 0.f, 0.f};
            const unsigned short* bp = wppT + (16 * wid + c) * 576 + q * 8;
            const unsigned short* ap = accL + c * 584 + q * 8;
#pragma unroll
            for (int kc = 0; kc < 18; ++kc) {
                bf16x8 af = *(const bf16x8*)(ap + kc * 32);
                bf16x8 bf = *(const bf16x8*)(bp + kc * 32);
                dacc = __builtin_amdgcn_mfma_f32_16x16x32_bf16(af, bf, dacc, 0, 0, 0);
            }
#pragma unroll
            for (int rr = 0; rr < 4; ++rr) {
                int node = bb * 16 + q * 4 + rr;
                int col = 16 * wid + c;
                out[node * 64 + col] = x[node * 64 + col] + dacc[rr];
            }
        }
    }
}

extern "C" void kernel_launch(void* const* d_in, const int* in_sizes, int n_in,
                              void* d_out, int out_size, void* d_ws, size_t ws_size,
                              hipStream_t stream) {
    const float* x     = (const float*)d_in[0];
    const int*   ei    = (const int*)d_in[1];
    /* d_in[2] edge_vec unused by reference */
    const float* el    = (const float*)d_in[3];
    const float* wproj = (const float*)d_in[4];
    const float* wrad  = (const float*)d_in[5];
    const float* wtan  = (const float*)d_in[6];
    const float* rsc   = (const float*)d_in[7];
    const float* tsc   = (const float*)d_in[8];
    const float* rdls  = (const float*)d_in[9];
    const float* tb    = (const float*)d_in[10];
    const float* tw    = (const float*)d_in[11];
    const float* wout  = (const float*)d_in[12];
    float* out = (float*)d_out;

    char* w = (char*)d_ws;
    size_t o = 0;
    auto nxt = [&](size_t bytes) -> char* {
        char* p = w + o;
        o += (bytes + 255) & ~(size_t)255;
        return p;
    };
    float* rts = (float*)nxt((size_t)N_NODES * 8 * 4);
    int*   cur = (int*)nxt((size_t)N_NODES * 4);
    int2*  sbuf = (int2*)nxt((size_t)N_NODES * CAP * 8);
    unsigned short* wppT = (unsigned short*)nxt((size_t)64 * 576 * 2);

    k_fused<<<GRID, 1024, 0, stream>>>(x, ei, el, wproj, wrad, wtan, rsc, tsc,
                                       rdls, tb, tw, wout,
                                       rts, cur, sbuf, wppT, out);
}

// Round 9
// 184.811 us; speedup vs baseline: 1.2430x; 1.2430x over previous
//
#include <hip/hip_runtime.h>
#include <math.h>

#define N_NODES 10000
#define N_EDGES 160000
#define CAP 64
#define GRID 512

typedef short bf16x8 __attribute__((ext_vector_type(8)));
typedef float f32x4 __attribute__((ext_vector_type(4)));

// ---------- helpers ----------
__device__ __forceinline__ float bf2f(unsigned short u) {
    return __uint_as_float(((unsigned int)u) << 16);
}
__device__ __forceinline__ unsigned short f2bf(float f) {
    unsigned int x = __float_as_uint(f);
    unsigned int r = (x + 0x7fffu + ((x >> 16) & 1u)) >> 16;   // RNE
    return (unsigned short)r;
}
__device__ __forceinline__ float softplus_f(float x) {
    return fmaxf(x, 0.f) + log1pf(__expf(-fabsf(x)));
}

// agent-scope relaxed 8B load/store: LLC-coherent, NO wbl2/inv (the R8 killer).
__device__ __forceinline__ unsigned long long ald64(const void* p) {
    return __hip_atomic_load((const unsigned long long*)p, __ATOMIC_RELAXED,
                             __HIP_MEMORY_SCOPE_AGENT);
}
__device__ __forceinline__ void ast64(void* p, unsigned long long v) {
    __hip_atomic_store((unsigned long long*)p, v, __ATOMIC_RELAXED,
                       __HIP_MEMORY_SCOPE_AGENT);
}
__device__ __forceinline__ unsigned long long packf2(float a, float b) {
    return (unsigned long long)__float_as_uint(a) |
           ((unsigned long long)__float_as_uint(b) << 32);
}
__device__ __forceinline__ float lof(unsigned long long q) { return __uint_as_float((unsigned int)q); }
__device__ __forceinline__ float hif(unsigned long long q) { return __uint_as_float((unsigned int)(q >> 32)); }

// ---------- fence-free two-level grid barrier (relaxed atomics only) ----------
// Telescoping counts: no reset needed across episodes/launches.
__device__ unsigned int g_grp[64];
__device__ unsigned int g_root = 0;
__device__ unsigned int g_sense2 = 0;

__device__ __forceinline__ void gbar() {
    __syncthreads();   // drains vmcnt(0): all block's atomic stores LLC-acked
    if (threadIdx.x == 0) {
        unsigned int e = __hip_atomic_load(&g_sense2, __ATOMIC_RELAXED, __HIP_MEMORY_SCOPE_AGENT);
        int g = blockIdx.x & 63;
        unsigned int old = __hip_atomic_fetch_add(&g_grp[g], 1, __ATOMIC_RELAXED, __HIP_MEMORY_SCOPE_AGENT);
        if ((old & 7) == 7) {                 // last of 8 in group
            unsigned int ro = __hip_atomic_fetch_add(&g_root, 1, __ATOMIC_RELAXED, __HIP_MEMORY_SCOPE_AGENT);
            if ((ro & 63) == 63)              // last of 64 groups
                __hip_atomic_fetch_add(&g_sense2, 1, __ATOMIC_RELAXED, __HIP_MEMORY_SCOPE_AGENT);
        }
        while (__hip_atomic_load(&g_sense2, __ATOMIC_RELAXED, __HIP_MEMORY_SCOPE_AGENT) == e)
            __builtin_amdgcn_s_sleep(2);
    }
    __syncthreads();
}

// ---------- the whole layer, one launch ----------
__global__ void __launch_bounds__(1024, 8) k_fused(const float* __restrict__ x,
                                                   const int* __restrict__ ei,
                                                   const float* __restrict__ el,
                                                   const float* __restrict__ wproj,
                                                   const float* __restrict__ wrad,
                                                   const float* __restrict__ wtan,
                                                   const float* __restrict__ rsc,
                                                   const float* __restrict__ tsc,
                                                   const float* __restrict__ rdls,
                                                   const float* __restrict__ tb,
                                                   const float* __restrict__ tw,
                                                   const float* __restrict__ wout,
                                                   float* __restrict__ rts,
                                                   unsigned int* __restrict__ cur,
                                                   unsigned long long* __restrict__ sbuf,
                                                   unsigned short* __restrict__ wppT,
                                                   float* __restrict__ out) {
    __shared__ __align__(16) char smem[55552];
    int b = blockIdx.x;
    int t = threadIdx.x;
    int wid = t >> 6, lane = t & 63;

    // ---- phase 0: zero bucket counters (atomic stores -> LLC) ----
#pragma unroll
    for (int k = 0; k < 20; ++k) {
        int idx = b * 20 + k;
        if (idx < N_NODES)
            __hip_atomic_store(&cur[idx], 0u, __ATOMIC_RELAXED, __HIP_MEMORY_SCOPE_AGENT);
    }
    gbar();

    // ---- phase 1: bucket (all blocks) | score (blocks 0..19) | W'' (20..28) ----
    {   // bucket: 313 edges per block
        int e = b * 313 + t;
        if (t < 313 && e < N_EDGES) {
            int s = ei[e];
            int r = ei[N_EDGES + e];
            float len = el[e];
            unsigned int pos = atomicAdd(&cur[r], 1u);
            if (pos < CAP)
                ast64(&sbuf[r * CAP + pos],
                      (unsigned long long)(unsigned int)s |
                      ((unsigned long long)__float_as_uint(len) << 32));
        }
    }
    if (b < 20) {
        // scores -> rts[n][0..3]=r, [4..7]=t (f32 exact path), atomic 8B stores
        float* vrl = (float*)smem;            // 256 floats
        float* vtl = vrl + 256;
        if (t < 256) {
            int h = t >> 6, f = t & 63;
            const float* wrow = wproj + h * 4096 + f * 64;
            const float* rsp = rsc + h * 64;
            const float* tsp = tsc + h * 64;
            float ar = 0.f, at = 0.f;
            for (int g = 0; g < 64; ++g) {
                float w = wrow[g];
                ar += w * rsp[g];
                at += w * tsp[g];
            }
            vrl[t] = ar;
            vtl[t] = at;
        }
        __syncthreads();
        if (t < 512) {
            int n = b * 512 + t;
            if (n < N_NODES) {
                const float4* xr = (const float4*)(x + n * 64);
                float accr[4] = {0.f, 0.f, 0.f, 0.f};
                float acct[4] = {0.f, 0.f, 0.f, 0.f};
                for (int i = 0; i < 16; ++i) {
                    float4 xv = xr[i];
#pragma unroll
                    for (int h = 0; h < 4; ++h) {
                        float4 a = ((const float4*)vrl)[h * 16 + i];
                        accr[h] += xv.x * a.x + xv.y * a.y + xv.z * a.z + xv.w * a.w;
                        float4 bb = ((const float4*)vtl)[h * 16 + i];
                        acct[h] += xv.x * bb.x + xv.y * bb.y + xv.z * bb.z + xv.w * bb.w;
                    }
                }
                ast64(rts + n * 8 + 0, packf2(accr[0], accr[1]));
                ast64(rts + n * 8 + 2, packf2(accr[2], accr[3]));
                ast64(rts + n * 8 + 4, packf2(acct[0], acct[1]));
                ast64(rts + n * 8 + 6, packf2(acct[2], acct[3]));
            }
        }
    } else if (b < 29) {
        // W'': W''_k = Wk @ Wout * 0.25 (k=8: -sum), transposed bf16, atomic 8B stores
        int k = b - 20;                       // 0..8
        float* wo = (float*)smem;             // wout [g][c], 16 KB
        float* am = wo + 4096;                // A    [f][g], 16 KB
        for (int i = 0; i < 4; ++i) wo[t + 1024 * i] = wout[t + 1024 * i];
        if (k < 8) {
            const float* M = (k < 4) ? (wrad + k * 4096) : (wtan + (k - 4) * 4096);
            for (int i = 0; i < 4; ++i) am[t + 1024 * i] = M[t + 1024 * i];
        } else {
            for (int i = 0; i < 4; ++i) {
                int e = t + 1024 * i;
                float s = 0.f;
#pragma unroll
                for (int h = 0; h < 4; ++h) s += wrad[h * 4096 + e] + wtan[h * 4096 + e];
                am[e] = -s;
            }
        }
        __syncthreads();
        int c = t & 63;
        int fg = t >> 6;                      // 0..15, covers f = fg*4..fg*4+3
        float r4[4];
#pragma unroll
        for (int j = 0; j < 4; ++j) {
            int f = fg * 4 + j;
            float acc = 0.f;
            for (int g = 0; g < 64; ++g) acc += am[f * 64 + g] * wo[g * 64 + c];
            r4[j] = acc * 0.25f;
        }
        unsigned long long q = (unsigned long long)f2bf(r4[0]) |
                               ((unsigned long long)f2bf(r4[1]) << 16) |
                               ((unsigned long long)f2bf(r4[2]) << 32) |
                               ((unsigned long long)f2bf(r4[3]) << 48);
        ast64(wppT + c * 576 + k * 64 + fg * 4, q);
    }
    gbar();

    // ---- phase 2: 625 16-node tiles over 512 blocks (blocks 0..112 run 2 rounds) ----
    float* aldsb = (float*)smem;
    unsigned short* accL = (unsigned short*)(smem + 32768);
    int* sldsb = (int*)(smem + 51456);
    float* alds = aldsb + wid * 512;
    int*   slds = sldsb + wid * 64;

    float scale = softplus_f(rdls[0]);
    float tb0 = tb[0], tb1 = tb[1], tb2 = tb[2], tb3 = tb[3];
    float tw0 = tw[0], tw1 = tw[1], tw2 = tw[2], tw3 = tw[3];

    for (int r = 0; r < 2; ++r) {
        int bb = b + r * GRID;
        if (bb >= 625) break;                  // block-uniform
        if (r == 1) __syncthreads();           // round-0 accL reads done
        int n = bb * 16 + wid;
        unsigned int dv = __hip_atomic_load(&cur[n], __ATOMIC_RELAXED, __HIP_MEMORY_SCOPE_AGENT);
        int deg = min((int)dv, CAP);

        unsigned long long rq0 = ald64(rts + n * 8 + 0), rq1 = ald64(rts + n * 8 + 2);
        unsigned long long rq2 = ald64(rts + n * 8 + 4), rq3 = ald64(rts + n * 8 + 6);
        float rsr0 = lof(rq0), rsr1 = hif(rq0), rsr2 = lof(rq1), rsr3 = hif(rq1);
        float tsr0 = lof(rq2), tsr1 = hif(rq2), tsr2 = lof(rq3), tsr3 = hif(rq3);

        const float NEG = -3.402823466e38f;
        float rl0 = NEG, rl1 = NEG, rl2 = NEG, rl3 = NEG;
        float tl0 = NEG, tl1 = NEG, tl2 = NEG, tl3 = NEG;
        int s_e = 0;
        if (lane < deg) {
            unsigned long long sq = ald64(&sbuf[n * CAP + lane]);
            s_e = (int)(unsigned int)sq;
            float len = __uint_as_float((unsigned int)(sq >> 32));
            unsigned long long q0 = ald64(rts + s_e * 8 + 0), q1 = ald64(rts + s_e * 8 + 2);
            unsigned long long q2 = ald64(rts + s_e * 8 + 4), q3 = ald64(rts + s_e * 8 + 6);
            float sl0 = scale * len;
            float i0 = 1.f / (softplus_f(tb0 + tw0 * len) + 1e-4f);
            float i1 = 1.f / (softplus_f(tb1 + tw1 * len) + 1e-4f);
            float i2 = 1.f / (softplus_f(tb2 + tw2 * len) + 1e-4f);
            float i3 = 1.f / (softplus_f(tb3 + tw3 * len) + 1e-4f);
            rl0 = ((lof(q0) - rsr0) - sl0) * i0;
            rl1 = ((hif(q0) - rsr1) - sl0) * i1;
            rl2 = ((lof(q1) - rsr2) - sl0) * i2;
            rl3 = ((hif(q1) - rsr3) - sl0) * i3;
            tl0 = lof(q2) - tsr0;
            tl1 = hif(q2) - tsr1;
            tl2 = lof(q3) - tsr2;
            tl3 = hif(q3) - tsr3;
        }
        float mr0 = rl0, mr1 = rl1, mr2 = rl2, mr3 = rl3;
        float mt0 = tl0, mt1 = tl1, mt2 = tl2, mt3 = tl3;
#pragma unroll
        for (int d = 32; d >= 1; d >>= 1) {
            mr0 = fmaxf(mr0, __shfl_xor(mr0, d)); mr1 = fmaxf(mr1, __shfl_xor(mr1, d));
            mr2 = fmaxf(mr2, __shfl_xor(mr2, d)); mr3 = fmaxf(mr3, __shfl_xor(mr3, d));
            mt0 = fmaxf(mt0, __shfl_xor(mt0, d)); mt1 = fmaxf(mt1, __shfl_xor(mt1, d));
            mt2 = fmaxf(mt2, __shfl_xor(mt2, d)); mt3 = fmaxf(mt3, __shfl_xor(mt3, d));
        }
        float er0 = 0.f, er1 = 0.f, er2 = 0.f, er3 = 0.f;
        float et0 = 0.f, et1 = 0.f, et2 = 0.f, et3 = 0.f;
        if (lane < deg) {
            er0 = __expf(rl0 - mr0); er1 = __expf(rl1 - mr1);
            er2 = __expf(rl2 - mr2); er3 = __expf(rl3 - mr3);
            et0 = __expf(tl0 - mt0); et1 = __expf(tl1 - mt1);
            et2 = __expf(tl2 - mt2); et3 = __expf(tl3 - mt3);
        }
        float sr0 = er0, sr1 = er1, sr2 = er2, sr3 = er3;
        float st0 = et0, st1 = et1, st2 = et2, st3 = et3;
#pragma unroll
        for (int d = 32; d >= 1; d >>= 1) {
            sr0 += __shfl_xor(sr0, d); sr1 += __shfl_xor(sr1, d);
            sr2 += __shfl_xor(sr2, d); sr3 += __shfl_xor(sr3, d);
            st0 += __shfl_xor(st0, d); st1 += __shfl_xor(st1, d);
            st2 += __shfl_xor(st2, d); st3 += __shfl_xor(st3, d);
        }
        if (lane < deg) {
            float* ap = alds + lane * 8;
            ((float4*)ap)[0] = make_float4(er0 / sr0, er1 / sr1, er2 / sr2, er3 / sr3);
            ((float4*)ap)[1] = make_float4(et0 / st0, et1 / st1, et2 / st2, et3 / st3);
            slds[lane] = s_e;
        }

        // accumulate V row: lane = feature f; 9 accumulators; 4-way unrolled
        float a0 = 0.f, a1 = 0.f, a2 = 0.f, a3 = 0.f;
        float b0 = 0.f, b1 = 0.f, b2 = 0.f, b3 = 0.f;
        int i = 0;
        for (; i + 4 <= deg; i += 4) {
            int s0 = slds[i], s1 = slds[i + 1], s2 = slds[i + 2], s3 = slds[i + 3];
            float xv0 = x[s0 * 64 + lane];
            float xv1 = x[s1 * 64 + lane];
            float xv2 = x[s2 * 64 + lane];
            float xv3 = x[s3 * 64 + lane];
            float4 ar0 = ((const float4*)(alds + i * 8))[0];
            float4 at0 = ((const float4*)(alds + i * 8))[1];
            float4 ar1 = ((const float4*)(alds + (i + 1) * 8))[0];
            float4 at1 = ((const float4*)(alds + (i + 1) * 8))[1];
            float4 ar2 = ((const float4*)(alds + (i + 2) * 8))[0];
            float4 at2 = ((const float4*)(alds + (i + 2) * 8))[1];
            float4 ar3 = ((const float4*)(alds + (i + 3) * 8))[0];
            float4 at3 = ((const float4*)(alds + (i + 3) * 8))[1];
            a0 += ar0.x * xv0 + ar1.x * xv1 + ar2.x * xv2 + ar3.x * xv3;
            a1 += ar0.y * xv0 + ar1.y * xv1 + ar2.y * xv2 + ar3.y * xv3;
            a2 += ar0.z * xv0 + ar1.z * xv1 + ar2.z * xv2 + ar3.z * xv3;
            a3 += ar0.w * xv0 + ar1.w * xv1 + ar2.w * xv2 + ar3.w * xv3;
            b0 += at0.x * xv0 + at1.x * xv1 + at2.x * xv2 + at3.x * xv3;
            b1 += at0.y * xv0 + at1.y * xv1 + at2.y * xv2 + at3.y * xv3;
            b2 += at0.z * xv0 + at1.z * xv1 + at2.z * xv2 + at3.z * xv3;
            b3 += at0.w * xv0 + at1.w * xv1 + at2.w * xv2 + at3.w * xv3;
        }
        for (; i < deg; ++i) {
            int s0 = slds[i];
            float xv0 = x[s0 * 64 + lane];
            float4 ar0 = ((const float4*)(alds + i * 8))[0];
            float4 at0 = ((const float4*)(alds + i * 8))[1];
            a0 += ar0.x * xv0; a1 += ar0.y * xv0; a2 += ar0.z * xv0; a3 += ar0.w * xv0;
            b0 += at0.x * xv0; b1 += at0.y * xv0; b2 += at0.z * xv0; b3 += at0.w * xv0;
        }
        float c8 = (deg > 0) ? x[n * 64 + lane] : 0.f;   // receiver slot (sign in W''_8)

        unsigned short* arow = accL + wid * 584;
        arow[0 * 64 + lane] = f2bf(a0);
        arow[1 * 64 + lane] = f2bf(a1);
        arow[2 * 64 + lane] = f2bf(a2);
        arow[3 * 64 + lane] = f2bf(a3);
        arow[4 * 64 + lane] = f2bf(b0);
        arow[5 * 64 + lane] = f2bf(b1);
        arow[6 * 64 + lane] = f2bf(b2);
        arow[7 * 64 + lane] = f2bf(b3);
        arow[8 * 64 + lane] = f2bf(c8);
        __syncthreads();

        // stage B: [16 x 576] @ W''T -> out[16 x 64]; waves 0..3
        if (wid < 4) {
            int c = lane & 15, q = lane >> 4;
            f32x4 dacc = {0.f, 0.f, 0.f, 0.f};
            const unsigned short* bp = wppT + (16 * wid + c) * 576 + q * 8;
            const unsigned short* ap = accL + c * 584 + q * 8;
#pragma unroll
            for (int kc = 0; kc < 18; ++kc) {
                union { unsigned long long q2[2]; bf16x8 v; } ub;
                ub.q2[0] = ald64(bp + kc * 32);
                ub.q2[1] = ald64(bp + kc * 32 + 4);
                bf16x8 af = *(const bf16x8*)(ap + kc * 32);
                dacc = __builtin_amdgcn_mfma_f32_16x16x32_bf16(af, ub.v, dacc, 0, 0, 0);
            }
#pragma unroll
            for (int rr = 0; rr < 4; ++rr) {
                int node = bb * 16 + q * 4 + rr;
                int col = 16 * wid + c;
                out[node * 64 + col] = x[node * 64 + col] + dacc[rr];
            }
        }
    }
}

extern "C" void kernel_launch(void* const* d_in, const int* in_sizes, int n_in,
                              void* d_out, int out_size, void* d_ws, size_t ws_size,
                              hipStream_t stream) {
    const float* x     = (const float*)d_in[0];
    const int*   ei    = (const int*)d_in[1];
    /* d_in[2] edge_vec unused by reference */
    const float* el    = (const float*)d_in[3];
    const float* wproj = (const float*)d_in[4];
    const float* wrad  = (const float*)d_in[5];
    const float* wtan  = (const float*)d_in[6];
    const float* rsc   = (const float*)d_in[7];
    const float* tsc   = (const float*)d_in[8];
    const float* rdls  = (const float*)d_in[9];
    const float* tb    = (const float*)d_in[10];
    const float* tw    = (const float*)d_in[11];
    const float* wout  = (const float*)d_in[12];
    float* out = (float*)d_out;

    char* w = (char*)d_ws;
    size_t o = 0;
    auto nxt = [&](size_t bytes) -> char* {
        char* p = w + o;
        o += (bytes + 255) & ~(size_t)255;
        return p;
    };
    float* rts = (float*)nxt((size_t)N_NODES * 8 * 4);
    unsigned int* cur = (unsigned int*)nxt((size_t)N_NODES * 4);
    unsigned long long* sbuf = (unsigned long long*)nxt((size_t)N_NODES * CAP * 8);
    unsigned short* wppT = (unsigned short*)nxt((size_t)64 * 576 * 2);

    k_fused<<<GRID, 1024, 0, stream>>>(x, ei, el, wproj, wrad, wtan, rsc, tsc,
                                       rdls, tb, tw, wout,
                                       rts, cur, sbuf, wppT, out);
}

// Round 10
// 122.372 us; speedup vs baseline: 1.8772x; 1.5102x over previous
//
#include <hip/hip_runtime.h>
#include <math.h>

#define N_NODES 10000
#define N_EDGES 160000
#define CAP 64

// D1 task split
#define NB_SCORE 40
#define NB_BUCKET 625
#define NB_WPP 9
#define NB_D1 (NB_SCORE + NB_BUCKET + NB_WPP)

typedef short bf16x8 __attribute__((ext_vector_type(8)));
typedef float f32x4 __attribute__((ext_vector_type(4)));

// Self-resetting bucket counters: zero-initialized at module load; k_node
// resets each entry after consuming it, so every launch (correctness call,
// graph replays) starts from all-zero without a memset dispatch.
__device__ int g_cur[N_NODES];

// ---------- helpers ----------
__device__ __forceinline__ float bf2f(unsigned short u) {
    return __uint_as_float(((unsigned int)u) << 16);
}
__device__ __forceinline__ unsigned short f2bf(float f) {
    unsigned int x = __float_as_uint(f);
    unsigned int r = (x + 0x7fffu + ((x >> 16) & 1u)) >> 16;   // RNE
    return (unsigned short)r;
}
__device__ __forceinline__ float softplus_f(float x) {
    return fmaxf(x, 0.f) + log1pf(__expf(-fabsf(x)));
}

// ---------- D1: scores | bucket | W'' precompute ----------
// W''_k = Wk @ Wout * 0.25 (k=0..3: Wr[h]; k=4..7: Wt[h]; k=8: -sum of all 8),
// stored TRANSPOSED: wppT[c*576 + k*64 + f] (bf16), c = out column.
__global__ void __launch_bounds__(256) k_prep(const float* __restrict__ x,
                                              const float* __restrict__ wproj,
                                              const float* __restrict__ wrad,
                                              const float* __restrict__ wtan,
                                              const float* __restrict__ rsc,
                                              const float* __restrict__ tsc,
                                              const float* __restrict__ wout,
                                              const int* __restrict__ ei,
                                              const float* __restrict__ el,
                                              float* __restrict__ rts,
                                              int2* __restrict__ sbuf,
                                              unsigned short* __restrict__ wppT) {
    __shared__ __align__(16) float smem[8192];   // 32 KB
    int b = blockIdx.x;
    int t = threadIdx.x;

    if (b < NB_SCORE) {
        // ---- per-node logit scalars rts[n][0..3]=r, [4..7]=t (f32 exact path) ----
        float* vrl = smem;            // 256 floats
        float* vtl = smem + 256;
        {
            int h = t >> 6, f = t & 63;
            const float* wrow = wproj + h * 4096 + f * 64;
            const float* rsp = rsc + h * 64;
            const float* tsp = tsc + h * 64;
            float ar = 0.f, at = 0.f;
            for (int g = 0; g < 64; ++g) {
                float w = wrow[g];
                ar += w * rsp[g];
                at += w * tsp[g];
            }
            vrl[t] = ar;
            vtl[t] = at;
        }
        __syncthreads();
        int n = b * 256 + t;
        if (n >= N_NODES) return;
        const float4* xr = (const float4*)(x + n * 64);
        float accr[4] = {0.f, 0.f, 0.f, 0.f};
        float acct[4] = {0.f, 0.f, 0.f, 0.f};
        for (int i = 0; i < 16; ++i) {
            float4 xv = xr[i];
#pragma unroll
            for (int h = 0; h < 4; ++h) {
                float4 a = ((const float4*)vrl)[h * 16 + i];
                accr[h] += xv.x * a.x + xv.y * a.y + xv.z * a.z + xv.w * a.w;
                float4 bb = ((const float4*)vtl)[h * 16 + i];
                acct[h] += xv.x * bb.x + xv.y * bb.y + xv.z * bb.z + xv.w * bb.w;
            }
        }
        ((float4*)rts)[n * 2]     = make_float4(accr[0], accr[1], accr[2], accr[3]);
        ((float4*)rts)[n * 2 + 1] = make_float4(acct[0], acct[1], acct[2], acct[3]);
    } else if (b < NB_SCORE + NB_BUCKET) {
        // ---- bucket edges by receiver (g_cur starts all-zero by invariant) ----
        int e = (b - NB_SCORE) * 256 + t;
        if (e >= N_EDGES) return;
        int s = ei[e];
        int r = ei[N_EDGES + e];
        float len = el[e];
        int pos = atomicAdd(&g_cur[r], 1);
        if (pos < CAP) sbuf[r * CAP + pos] = make_int2(s, __float_as_int(len));
    } else {
        // ---- W'' precompute, one 64x64x64 f32 GEMM per task ----
        int k = b - NB_SCORE - NB_BUCKET;     // 0..8
        float* wo = smem;                     // wout [g][c]
        float* am = smem + 4096;              // A    [f][g]
        for (int i = 0; i < 16; ++i) wo[t + 256 * i] = wout[t + 256 * i];
        if (k < 8) {
            const float* M = (k < 4) ? (wrad + k * 4096) : (wtan + (k - 4) * 4096);
            for (int i = 0; i < 16; ++i) am[t + 256 * i] = M[t + 256 * i];
        } else {
            for (int i = 0; i < 16; ++i) {
                int e = t + 256 * i;
                float s = 0.f;
#pragma unroll
                for (int h = 0; h < 4; ++h) s += wrad[h * 4096 + e] + wtan[h * 4096 + e];
                am[e] = -s;
            }
        }
        __syncthreads();
        int c = t & 63;
        int fg = t >> 6;                      // 0..3
        for (int j = 0; j < 16; ++j) {
            int f = fg * 16 + j;
            float acc = 0.f;
            for (int g = 0; g < 64; ++g) acc += am[f * 64 + g] * wo[g * 64 + c];
            wppT[c * 576 + k * 64 + f] = f2bf(acc * 0.25f);
        }
    }
}

// ---------- D2: softmax + alpha-weighted x-sums + fused output GEMM (MFMA) ----------
// Block = 1024 threads = 16 waves = 16 nodes (1 node/wave for latency hiding).
__global__ void __launch_bounds__(1024, 8) k_node(const int2* __restrict__ sbuf,
                                                  const float* __restrict__ rts,
                                                  const float* __restrict__ rdls,
                                                  const float* __restrict__ tb,
                                                  const float* __restrict__ tw,
                                                  const float* __restrict__ x,
                                                  const unsigned short* __restrict__ wppT,
                                                  float* __restrict__ out) {
    __shared__ __align__(16) unsigned short accL[16 * 584];   // 18688 B
    __shared__ __align__(16) float aldsb[16][CAP * 8];        // 32768 B
    __shared__ int sldsb[16][CAP];                            // 4096 B
    int t = threadIdx.x;
    int wid = t >> 6, lane = t & 63;
    int blk = blockIdx.x;

    float scale = softplus_f(rdls[0]);
    float tb0 = tb[0], tb1 = tb[1], tb2 = tb[2], tb3 = tb[3];
    float tw0 = tw[0], tw1 = tw[1], tw2 = tw[2], tw3 = tw[3];
    float* alds = aldsb[wid];
    int*   slds = sldsb[wid];

    int n = blk * 16 + wid;                   // 625*16 == N_NODES exactly
    int deg = min(g_cur[n], CAP);
    if (lane == 0) g_cur[n] = 0;              // reset for next launch

    float4 rsr = ((const float4*)rts)[n * 2];
    float4 tsr = ((const float4*)rts)[n * 2 + 1];

    const float NEG = -3.402823466e38f;
    float rl0 = NEG, rl1 = NEG, rl2 = NEG, rl3 = NEG;
    float tl0 = NEG, tl1 = NEG, tl2 = NEG, tl3 = NEG;
    int s_e = 0;
    if (lane < deg) {
        int2 sl = sbuf[n * CAP + lane];
        s_e = sl.x;
        float len = __int_as_float(sl.y);
        float4 rss = ((const float4*)rts)[s_e * 2];
        float4 tss = ((const float4*)rts)[s_e * 2 + 1];
        float sl0 = scale * len;
        float i0 = 1.f / (softplus_f(tb0 + tw0 * len) + 1e-4f);
        float i1 = 1.f / (softplus_f(tb1 + tw1 * len) + 1e-4f);
        float i2 = 1.f / (softplus_f(tb2 + tw2 * len) + 1e-4f);
        float i3 = 1.f / (softplus_f(tb3 + tw3 * len) + 1e-4f);
        rl0 = ((rss.x - rsr.x) - sl0) * i0;
        rl1 = ((rss.y - rsr.y) - sl0) * i1;
        rl2 = ((rss.z - rsr.z) - sl0) * i2;
        rl3 = ((rss.w - rsr.w) - sl0) * i3;
        tl0 = tss.x - tsr.x;
        tl1 = tss.y - tsr.y;
        tl2 = tss.z - tsr.z;
        tl3 = tss.w - tsr.w;
    }
    float mr0 = rl0, mr1 = rl1, mr2 = rl2, mr3 = rl3;
    float mt0 = tl0, mt1 = tl1, mt2 = tl2, mt3 = tl3;
#pragma unroll
    for (int d = 32; d >= 1; d >>= 1) {
        mr0 = fmaxf(mr0, __shfl_xor(mr0, d)); mr1 = fmaxf(mr1, __shfl_xor(mr1, d));
        mr2 = fmaxf(mr2, __shfl_xor(mr2, d)); mr3 = fmaxf(mr3, __shfl_xor(mr3, d));
        mt0 = fmaxf(mt0, __shfl_xor(mt0, d)); mt1 = fmaxf(mt1, __shfl_xor(mt1, d));
        mt2 = fmaxf(mt2, __shfl_xor(mt2, d)); mt3 = fmaxf(mt3, __shfl_xor(mt3, d));
    }
    float er0 = 0.f, er1 = 0.f, er2 = 0.f, er3 = 0.f;
    float et0 = 0.f, et1 = 0.f, et2 = 0.f, et3 = 0.f;
    if (lane < deg) {
        er0 = __expf(rl0 - mr0); er1 = __expf(rl1 - mr1);
        er2 = __expf(rl2 - mr2); er3 = __expf(rl3 - mr3);
        et0 = __expf(tl0 - mt0); et1 = __expf(tl1 - mt1);
        et2 = __expf(tl2 - mt2); et3 = __expf(tl3 - mt3);
    }
    float sr0 = er0, sr1 = er1, sr2 = er2, sr3 = er3;
    float st0 = et0, st1 = et1, st2 = et2, st3 = et3;
#pragma unroll
    for (int d = 32; d >= 1; d >>= 1) {
        sr0 += __shfl_xor(sr0, d); sr1 += __shfl_xor(sr1, d);
        sr2 += __shfl_xor(sr2, d); sr3 += __shfl_xor(sr3, d);
        st0 += __shfl_xor(st0, d); st1 += __shfl_xor(st1, d);
        st2 += __shfl_xor(st2, d); st3 += __shfl_xor(st3, d);
    }
    if (lane < deg) {
        float* ap = alds + lane * 8;
        ((float4*)ap)[0] = make_float4(er0 / sr0, er1 / sr1, er2 / sr2, er3 / sr3);
        ((float4*)ap)[1] = make_float4(et0 / st0, et1 / st1, et2 / st2, et3 / st3);
        slds[lane] = s_e;
    }

    // ---- accumulate V row: lane = feature f; 9 accumulators; 4-way unrolled ----
    float a0 = 0.f, a1 = 0.f, a2 = 0.f, a3 = 0.f;
    float b0 = 0.f, b1 = 0.f, b2 = 0.f, b3 = 0.f;
    int i = 0;
    for (; i + 4 <= deg; i += 4) {
        int s0 = slds[i], s1 = slds[i + 1], s2 = slds[i + 2], s3 = slds[i + 3];
        float xv0 = x[s0 * 64 + lane];
        float xv1 = x[s1 * 64 + lane];
        float xv2 = x[s2 * 64 + lane];
        float xv3 = x[s3 * 64 + lane];
        float4 ar0 = ((const float4*)(alds + i * 8))[0];
        float4 at0 = ((const float4*)(alds + i * 8))[1];
        float4 ar1 = ((const float4*)(alds + (i + 1) * 8))[0];
        float4 at1 = ((const float4*)(alds + (i + 1) * 8))[1];
        float4 ar2 = ((const float4*)(alds + (i + 2) * 8))[0];
        float4 at2 = ((const float4*)(alds + (i + 2) * 8))[1];
        float4 ar3 = ((const float4*)(alds + (i + 3) * 8))[0];
        float4 at3 = ((const float4*)(alds + (i + 3) * 8))[1];
        a0 += ar0.x * xv0 + ar1.x * xv1 + ar2.x * xv2 + ar3.x * xv3;
        a1 += ar0.y * xv0 + ar1.y * xv1 + ar2.y * xv2 + ar3.y * xv3;
        a2 += ar0.z * xv0 + ar1.z * xv1 + ar2.z * xv2 + ar3.z * xv3;
        a3 += ar0.w * xv0 + ar1.w * xv1 + ar2.w * xv2 + ar3.w * xv3;
        b0 += at0.x * xv0 + at1.x * xv1 + at2.x * xv2 + at3.x * xv3;
        b1 += at0.y * xv0 + at1.y * xv1 + at2.y * xv2 + at3.y * xv3;
        b2 += at0.z * xv0 + at1.z * xv1 + at2.z * xv2 + at3.z * xv3;
        b3 += at0.w * xv0 + at1.w * xv1 + at2.w * xv2 + at3.w * xv3;
    }
    for (; i < deg; ++i) {
        int s0 = slds[i];
        float xv0 = x[s0 * 64 + lane];
        float4 ar0 = ((const float4*)(alds + i * 8))[0];
        float4 at0 = ((const float4*)(alds + i * 8))[1];
        a0 += ar0.x * xv0; a1 += ar0.y * xv0; a2 += ar0.z * xv0; a3 += ar0.w * xv0;
        b0 += at0.x * xv0; b1 += at0.y * xv0; b2 += at0.z * xv0; b3 += at0.w * xv0;
    }
    float c8 = (deg > 0) ? x[n * 64 + lane] : 0.f;   // receiver slot (sign in W''_8)

    unsigned short* arow = accL + wid * 584;
    arow[0 * 64 + lane] = f2bf(a0);
    arow[1 * 64 + lane] = f2bf(a1);
    arow[2 * 64 + lane] = f2bf(a2);
    arow[3 * 64 + lane] = f2bf(a3);
    arow[4 * 64 + lane] = f2bf(b0);
    arow[5 * 64 + lane] = f2bf(b1);
    arow[6 * 64 + lane] = f2bf(b2);
    arow[7 * 64 + lane] = f2bf(b3);
    arow[8 * 64 + lane] = f2bf(c8);
    __syncthreads();

    // ---- stage B: [16 x 576] @ W''T -> out[16 x 64]; waves 0..3 ----
    if (wid < 4) {
        int c = lane & 15, q = lane >> 4;
        f32x4 dacc = {0.f, 0.f, 0.f, 0.f};
        const unsigned short* bp = wppT + (16 * wid + c) * 576 + q * 8;
        const unsigned short* ap = accL + c * 584 + q * 8;   // A: m = lane&15 (node row)
#pragma unroll
        for (int kc = 0; kc < 18; ++kc) {
            bf16x8 af = *(const bf16x8*)(ap + kc * 32);
            bf16x8 bf = *(const bf16x8*)(bp + kc * 32);
            dacc = __builtin_amdgcn_mfma_f32_16x16x32_bf16(af, bf, dacc, 0, 0, 0);
        }
#pragma unroll
        for (int r = 0; r < 4; ++r) {
            int node = blk * 16 + q * 4 + r;
            int col = 16 * wid + c;
            out[node * 64 + col] = x[node * 64 + col] + dacc[r];
        }
    }
}

extern "C" void kernel_launch(void* const* d_in, const int* in_sizes, int n_in,
                              void* d_out, int out_size, void* d_ws, size_t ws_size,
                              hipStream_t stream) {
    const float* x     = (const float*)d_in[0];
    const int*   ei    = (const int*)d_in[1];
    /* d_in[2] edge_vec unused by reference */
    const float* el    = (const float*)d_in[3];
    const float* wproj = (const float*)d_in[4];
    const float* wrad  = (const float*)d_in[5];
    const float* wtan  = (const float*)d_in[6];
    const float* rsc   = (const float*)d_in[7];
    const float* tsc   = (const float*)d_in[8];
    const float* rdls  = (const float*)d_in[9];
    const float* tb    = (const float*)d_in[10];
    const float* tw    = (const float*)d_in[11];
    const float* wout  = (const float*)d_in[12];
    float* out = (float*)d_out;

    char* w = (char*)d_ws;
    size_t o = 0;
    auto nxt = [&](size_t bytes) -> char* {
        char* p = w + o;
        o += (bytes + 255) & ~(size_t)255;
        return p;
    };
    float* rts = (float*)nxt((size_t)N_NODES * 8 * 4);
    int2*  sbuf = (int2*)nxt((size_t)N_NODES * CAP * 8);
    unsigned short* wppT = (unsigned short*)nxt((size_t)64 * 576 * 2);

    k_prep<<<NB_D1, 256, 0, stream>>>(x, wproj, wrad, wtan, rsc, tsc, wout,
                                      ei, el, rts, sbuf, wppT);
    k_node<<<625, 1024, 0, stream>>>(sbuf, rts, rdls, tb, tw, x, wppT, out);
}

// Round 11
// 120.684 us; speedup vs baseline: 1.9035x; 1.0140x over previous
//
#include <hip/hip_runtime.h>
#include <math.h>

#define N_NODES 10000
#define N_EDGES 160000
#define CAP 64

// D1 task split
#define NB_SCORE 40
#define NB_BUCKET 625
#define NB_WPP 9
#define NB_D1 (NB_SCORE + NB_BUCKET + NB_WPP)

typedef short bf16x8 __attribute__((ext_vector_type(8)));
typedef float f32x4 __attribute__((ext_vector_type(4)));

// Self-resetting bucket counters: zero-initialized at module load; k_node
// resets each entry after consuming it, so every launch (correctness call,
// graph replays) starts from all-zero without a memset dispatch.
__device__ int g_cur[N_NODES];

// ---------- helpers ----------
__device__ __forceinline__ float bf2f(unsigned short u) {
    return __uint_as_float(((unsigned int)u) << 16);
}
__device__ __forceinline__ unsigned short f2bf(float f) {
    unsigned int x = __float_as_uint(f);
    unsigned int r = (x + 0x7fffu + ((x >> 16) & 1u)) >> 16;   // RNE
    return (unsigned short)r;
}
__device__ __forceinline__ float softplus_f(float x) {
    return fmaxf(x, 0.f) + log1pf(__expf(-fabsf(x)));
}

// ---------- D1: scores | bucket | W'' precompute ----------
// W''_k = Wk @ Wout * 0.25 (k=0..3: Wr[h]; k=4..7: Wt[h]; k=8: -sum of all 8),
// stored TRANSPOSED: wppT[c*576 + k*64 + f] (bf16), c = out column.
__global__ void __launch_bounds__(256) k_prep(const float* __restrict__ x,
                                              const float* __restrict__ wproj,
                                              const float* __restrict__ wrad,
                                              const float* __restrict__ wtan,
                                              const float* __restrict__ rsc,
                                              const float* __restrict__ tsc,
                                              const float* __restrict__ wout,
                                              const int* __restrict__ ei,
                                              const float* __restrict__ el,
                                              float* __restrict__ rts,
                                              int2* __restrict__ sbuf,
                                              unsigned short* __restrict__ wppT) {
    __shared__ __align__(16) float smem[8192];   // 32 KB
    int b = blockIdx.x;
    int t = threadIdx.x;

    if (b < NB_SCORE) {
        // ---- per-node logit scalars rts[n][0..3]=r, [4..7]=t (f32 exact path) ----
        float* vrl = smem;            // 256 floats
        float* vtl = smem + 256;
        {
            int h = t >> 6, f = t & 63;
            const float* wrow = wproj + h * 4096 + f * 64;
            const float* rsp = rsc + h * 64;
            const float* tsp = tsc + h * 64;
            float ar = 0.f, at = 0.f;
            for (int g = 0; g < 64; ++g) {
                float w = wrow[g];
                ar += w * rsp[g];
                at += w * tsp[g];
            }
            vrl[t] = ar;
            vtl[t] = at;
        }
        __syncthreads();
        int n = b * 256 + t;
        if (n >= N_NODES) return;
        const float4* xr = (const float4*)(x + n * 64);
        float accr[4] = {0.f, 0.f, 0.f, 0.f};
        float acct[4] = {0.f, 0.f, 0.f, 0.f};
        for (int i = 0; i < 16; ++i) {
            float4 xv = xr[i];
#pragma unroll
            for (int h = 0; h < 4; ++h) {
                float4 a = ((const float4*)vrl)[h * 16 + i];
                accr[h] += xv.x * a.x + xv.y * a.y + xv.z * a.z + xv.w * a.w;
                float4 bb = ((const float4*)vtl)[h * 16 + i];
                acct[h] += xv.x * bb.x + xv.y * bb.y + xv.z * bb.z + xv.w * bb.w;
            }
        }
        ((float4*)rts)[n * 2]     = make_float4(accr[0], accr[1], accr[2], accr[3]);
        ((float4*)rts)[n * 2 + 1] = make_float4(acct[0], acct[1], acct[2], acct[3]);
    } else if (b < NB_SCORE + NB_BUCKET) {
        // ---- bucket edges by receiver (g_cur starts all-zero by invariant) ----
        int e = (b - NB_SCORE) * 256 + t;
        if (e >= N_EDGES) return;
        int s = ei[e];
        int r = ei[N_EDGES + e];
        float len = el[e];
        int pos = atomicAdd(&g_cur[r], 1);
        if (pos < CAP) sbuf[r * CAP + pos] = make_int2(s, __float_as_int(len));
    } else {
        // ---- W'' precompute, one 64x64x64 f32 GEMM per task ----
        int k = b - NB_SCORE - NB_BUCKET;     // 0..8
        float* wo = smem;                     // wout [g][c]
        float* am = smem + 4096;              // A    [f][g]
        for (int i = 0; i < 16; ++i) wo[t + 256 * i] = wout[t + 256 * i];
        if (k < 8) {
            const float* M = (k < 4) ? (wrad + k * 4096) : (wtan + (k - 4) * 4096);
            for (int i = 0; i < 16; ++i) am[t + 256 * i] = M[t + 256 * i];
        } else {
            for (int i = 0; i < 16; ++i) {
                int e = t + 256 * i;
                float s = 0.f;
#pragma unroll
                for (int h = 0; h < 4; ++h) s += wrad[h * 4096 + e] + wtan[h * 4096 + e];
                am[e] = -s;
            }
        }
        __syncthreads();
        int c = t & 63;
        int fg = t >> 6;                      // 0..3
        for (int j = 0; j < 16; ++j) {
            int f = fg * 16 + j;
            float acc = 0.f;
            for (int g = 0; g < 64; ++g) acc += am[f * 64 + g] * wo[g * 64 + c];
            wppT[c * 576 + k * 64 + f] = f2bf(acc * 0.25f);
        }
    }
}

// ---------- D2: softmax + alpha-weighted x-sums + fused output GEMM (MFMA) ----------
// Block = 512 threads = 8 waves = 8 nodes (1 node/wave), grid 1250.
// 4 blocks/CU (wave-capped) -> finer scheduling quantum, ~20% less tail than
// the 625x1024 shape. Stage B: 16x16 MFMA with A rows 8..15 unused (MFMA D
// rows depend only on matching A rows; stores guarded to rows < 8).
__global__ void __launch_bounds__(512, 8) k_node(const int2* __restrict__ sbuf,
                                                 const float* __restrict__ rts,
                                                 const float* __restrict__ rdls,
                                                 const float* __restrict__ tb,
                                                 const float* __restrict__ tw,
                                                 const float* __restrict__ x,
                                                 const unsigned short* __restrict__ wppT,
                                                 float* __restrict__ out) {
    __shared__ __align__(16) unsigned short accL[16 * 584];   // 18688 B (rows 8..15 unused)
    __shared__ __align__(16) float aldsb[8][CAP * 8];         // 16384 B
    __shared__ int sldsb[8][CAP];                             // 2048 B
    int t = threadIdx.x;
    int wid = t >> 6, lane = t & 63;
    int blk = blockIdx.x;

    float scale = softplus_f(rdls[0]);
    float tb0 = tb[0], tb1 = tb[1], tb2 = tb[2], tb3 = tb[3];
    float tw0 = tw[0], tw1 = tw[1], tw2 = tw[2], tw3 = tw[3];
    float* alds = aldsb[wid];
    int*   slds = sldsb[wid];

    int n = blk * 8 + wid;                    // 1250*8 == N_NODES exactly
    int deg = min(g_cur[n], CAP);
    if (lane == 0) g_cur[n] = 0;              // reset for next launch

    float4 rsr = ((const float4*)rts)[n * 2];
    float4 tsr = ((const float4*)rts)[n * 2 + 1];

    const float NEG = -3.402823466e38f;
    float rl0 = NEG, rl1 = NEG, rl2 = NEG, rl3 = NEG;
    float tl0 = NEG, tl1 = NEG, tl2 = NEG, tl3 = NEG;
    int s_e = 0;
    if (lane < deg) {
        int2 sl = sbuf[n * CAP + lane];
        s_e = sl.x;
        float len = __int_as_float(sl.y);
        float4 rss = ((const float4*)rts)[s_e * 2];
        float4 tss = ((const float4*)rts)[s_e * 2 + 1];
        float sl0 = scale * len;
        float i0 = 1.f / (softplus_f(tb0 + tw0 * len) + 1e-4f);
        float i1 = 1.f / (softplus_f(tb1 + tw1 * len) + 1e-4f);
        float i2 = 1.f / (softplus_f(tb2 + tw2 * len) + 1e-4f);
        float i3 = 1.f / (softplus_f(tb3 + tw3 * len) + 1e-4f);
        rl0 = ((rss.x - rsr.x) - sl0) * i0;
        rl1 = ((rss.y - rsr.y) - sl0) * i1;
        rl2 = ((rss.z - rsr.z) - sl0) * i2;
        rl3 = ((rss.w - rsr.w) - sl0) * i3;
        tl0 = tss.x - tsr.x;
        tl1 = tss.y - tsr.y;
        tl2 = tss.z - tsr.z;
        tl3 = tss.w - tsr.w;
    }
    float mr0 = rl0, mr1 = rl1, mr2 = rl2, mr3 = rl3;
    float mt0 = tl0, mt1 = tl1, mt2 = tl2, mt3 = tl3;
#pragma unroll
    for (int d = 32; d >= 1; d >>= 1) {
        mr0 = fmaxf(mr0, __shfl_xor(mr0, d)); mr1 = fmaxf(mr1, __shfl_xor(mr1, d));
        mr2 = fmaxf(mr2, __shfl_xor(mr2, d)); mr3 = fmaxf(mr3, __shfl_xor(mr3, d));
        mt0 = fmaxf(mt0, __shfl_xor(mt0, d)); mt1 = fmaxf(mt1, __shfl_xor(mt1, d));
        mt2 = fmaxf(mt2, __shfl_xor(mt2, d)); mt3 = fmaxf(mt3, __shfl_xor(mt3, d));
    }
    float er0 = 0.f, er1 = 0.f, er2 = 0.f, er3 = 0.f;
    float et0 = 0.f, et1 = 0.f, et2 = 0.f, et3 = 0.f;
    if (lane < deg) {
        er0 = __expf(rl0 - mr0); er1 = __expf(rl1 - mr1);
        er2 = __expf(rl2 - mr2); er3 = __expf(rl3 - mr3);
        et0 = __expf(tl0 - mt0); et1 = __expf(tl1 - mt1);
        et2 = __expf(tl2 - mt2); et3 = __expf(tl3 - mt3);
    }
    float sr0 = er0, sr1 = er1, sr2 = er2, sr3 = er3;
    float st0 = et0, st1 = et1, st2 = et2, st3 = et3;
#pragma unroll
    for (int d = 32; d >= 1; d >>= 1) {
        sr0 += __shfl_xor(sr0, d); sr1 += __shfl_xor(sr1, d);
        sr2 += __shfl_xor(sr2, d); sr3 += __shfl_xor(sr3, d);
        st0 += __shfl_xor(st0, d); st1 += __shfl_xor(st1, d);
        st2 += __shfl_xor(st2, d); st3 += __shfl_xor(st3, d);
    }
    if (lane < deg) {
        float* ap = alds + lane * 8;
        ((float4*)ap)[0] = make_float4(er0 / sr0, er1 / sr1, er2 / sr2, er3 / sr3);
        ((float4*)ap)[1] = make_float4(et0 / st0, et1 / st1, et2 / st2, et3 / st3);
        slds[lane] = s_e;
    }

    // ---- accumulate V row: lane = feature f; 9 accumulators; 4-way unrolled ----
    float a0 = 0.f, a1 = 0.f, a2 = 0.f, a3 = 0.f;
    float b0 = 0.f, b1 = 0.f, b2 = 0.f, b3 = 0.f;
    int i = 0;
    for (; i + 4 <= deg; i += 4) {
        int s0 = slds[i], s1 = slds[i + 1], s2 = slds[i + 2], s3 = slds[i + 3];
        float xv0 = x[s0 * 64 + lane];
        float xv1 = x[s1 * 64 + lane];
        float xv2 = x[s2 * 64 + lane];
        float xv3 = x[s3 * 64 + lane];
        float4 ar0 = ((const float4*)(alds + i * 8))[0];
        float4 at0 = ((const float4*)(alds + i * 8))[1];
        float4 ar1 = ((const float4*)(alds + (i + 1) * 8))[0];
        float4 at1 = ((const float4*)(alds + (i + 1) * 8))[1];
        float4 ar2 = ((const float4*)(alds + (i + 2) * 8))[0];
        float4 at2 = ((const float4*)(alds + (i + 2) * 8))[1];
        float4 ar3 = ((const float4*)(alds + (i + 3) * 8))[0];
        float4 at3 = ((const float4*)(alds + (i + 3) * 8))[1];
        a0 += ar0.x * xv0 + ar1.x * xv1 + ar2.x * xv2 + ar3.x * xv3;
        a1 += ar0.y * xv0 + ar1.y * xv1 + ar2.y * xv2 + ar3.y * xv3;
        a2 += ar0.z * xv0 + ar1.z * xv1 + ar2.z * xv2 + ar3.z * xv3;
        a3 += ar0.w * xv0 + ar1.w * xv1 + ar2.w * xv2 + ar3.w * xv3;
        b0 += at0.x * xv0 + at1.x * xv1 + at2.x * xv2 + at3.x * xv3;
        b1 += at0.y * xv0 + at1.y * xv1 + at2.y * xv2 + at3.y * xv3;
        b2 += at0.z * xv0 + at1.z * xv1 + at2.z * xv2 + at3.z * xv3;
        b3 += at0.w * xv0 + at1.w * xv1 + at2.w * xv2 + at3.w * xv3;
    }
    for (; i < deg; ++i) {
        int s0 = slds[i];
        float xv0 = x[s0 * 64 + lane];
        float4 ar0 = ((const float4*)(alds + i * 8))[0];
        float4 at0 = ((const float4*)(alds + i * 8))[1];
        a0 += ar0.x * xv0; a1 += ar0.y * xv0; a2 += ar0.z * xv0; a3 += ar0.w * xv0;
        b0 += at0.x * xv0; b1 += at0.y * xv0; b2 += at0.z * xv0; b3 += at0.w * xv0;
    }
    float c8 = (deg > 0) ? x[n * 64 + lane] : 0.f;   // receiver slot (sign in W''_8)

    unsigned short* arow = accL + wid * 584;
    arow[0 * 64 + lane] = f2bf(a0);
    arow[1 * 64 + lane] = f2bf(a1);
    arow[2 * 64 + lane] = f2bf(a2);
    arow[3 * 64 + lane] = f2bf(a3);
    arow[4 * 64 + lane] = f2bf(b0);
    arow[5 * 64 + lane] = f2bf(b1);
    arow[6 * 64 + lane] = f2bf(b2);
    arow[7 * 64 + lane] = f2bf(b3);
    arow[8 * 64 + lane] = f2bf(c8);
    __syncthreads();

    // ---- stage B: [8 x 576] @ W''T -> out[8 x 64]; waves 0..3 ----
    if (wid < 4) {
        int c = lane & 15, q = lane >> 4;
        f32x4 dacc = {0.f, 0.f, 0.f, 0.f};
        const unsigned short* bp = wppT + (16 * wid + c) * 576 + q * 8;
        const unsigned short* ap = accL + c * 584 + q * 8;   // A: m = lane&15 (node row)
#pragma unroll
        for (int kc = 0; kc < 18; ++kc) {
            bf16x8 af = *(const bf16x8*)(ap + kc * 32);
            bf16x8 bf = *(const bf16x8*)(bp + kc * 32);
            dacc = __builtin_amdgcn_mfma_f32_16x16x32_bf16(af, bf, dacc, 0, 0, 0);
        }
#pragma unroll
        for (int r = 0; r < 4; ++r) {
            int row = q * 4 + r;              // D row; rows 8..15 are garbage (unused A rows)
            if (row < 8) {
                int node = blk * 8 + row;
                int col = 16 * wid + c;
                out[node * 64 + col] = x[node * 64 + col] + dacc[r];
            }
        }
    }
}

extern "C" void kernel_launch(void* const* d_in, const int* in_sizes, int n_in,
                              void* d_out, int out_size, void* d_ws, size_t ws_size,
                              hipStream_t stream) {
    const float* x     = (const float*)d_in[0];
    const int*   ei    = (const int*)d_in[1];
    /* d_in[2] edge_vec unused by reference */
    const float* el    = (const float*)d_in[3];
    const float* wproj = (const float*)d_in[4];
    const float* wrad  = (const float*)d_in[5];
    const float* wtan  = (const float*)d_in[6];
    const float* rsc   = (const float*)d_in[7];
    const float* tsc   = (const float*)d_in[8];
    const float* rdls  = (const float*)d_in[9];
    const float* tb    = (const float*)d_in[10];
    const float* tw    = (const float*)d_in[11];
    const float* wout  = (const float*)d_in[12];
    float* out = (float*)d_out;

    char* w = (char*)d_ws;
    size_t o = 0;
    auto nxt = [&](size_t bytes) -> char* {
        char* p = w + o;
        o += (bytes + 255) & ~(size_t)255;
        return p;
    };
    float* rts = (float*)nxt((size_t)N_NODES * 8 * 4);
    int2*  sbuf = (int2*)nxt((size_t)N_NODES * CAP * 8);
    unsigned short* wppT = (unsigned short*)nxt((size_t)64 * 576 * 2);

    k_prep<<<NB_D1, 256, 0, stream>>>(x, wproj, wrad, wtan, rsc, tsc, wout,
                                      ei, el, rts, sbuf, wppT);
    k_node<<<1250, 512, 0, stream>>>(sbuf, rts, rdls, tb, tw, x, wppT, out);
}